// Round 2
// baseline (57.833 us; speedup 1.0000x reference)
//
#include <hip/hip_runtime.h>
#include <hip/hip_bf16.h>

// LoRA conv experts, algebraically collapsed:
//   out = sum_e p_e * Conv3x1(w_out_e) ( Conv1x3(w_in_e) (x) )
// Both convs are linear => fold experts into ONE rank-64 separable pair:
//   W1[(e,r)][kx*256+c] = p_e * w_in[e,r,c,0,kx]    (64 x 768)
//   W2[o][ky*64+(e,r)]  = w_out[e,o,r,ky,0]         (256 x 192)
//   hT = conv1x3(x, W1) stored TRANSPOSED+PADDED: hT[b][y+1][n][m], y-halo rows
//   zeroed, so conv3x1 staging is a branch-free vector copy.

typedef __bf16 bf16x8 __attribute__((ext_vector_type(8)));
typedef __bf16 bf16x4 __attribute__((ext_vector_type(4)));
typedef float  f32x4  __attribute__((ext_vector_type(4)));
typedef float  f32x4v __attribute__((ext_vector_type(4)));

#define CIN_  256
#define COUT_ 256
#define M1    64      // E*R
#define K1    768     // 3*CIN
#define K2    192     // 3*M1
#define CS    264     // xs row stride (shorts): 132 dwords, %32==4 -> optimal b128
#define HS    200     // hs row stride (shorts): 100 dwords, %32==4 -> optimal b128

static __device__ __forceinline__ unsigned short f2bf(float f) {
    union { float f; unsigned u; } v; v.f = f;
    unsigned r = v.u + 0x7FFFu + ((v.u >> 16) & 1u);
    return (unsigned short)(r >> 16);
}

// ------------- prep: fold probs, reorder, cast; zero hT halo rows ------------
__global__ void prep_weights(const float* __restrict__ probs,
                             const float* __restrict__ w_in,
                             const float* __restrict__ w_out,
                             unsigned short* __restrict__ W1,
                             unsigned short* __restrict__ W2,
                             unsigned short* __restrict__ hT) {
    int idx = blockIdx.x * blockDim.x + threadIdx.x;
    if (idx < M1 * K1) {
        // W1[er][kx*256+c] = p_e * w_in[(er*256+c)*3 + kx]
        int er = idx / K1, rem = idx % K1;
        int kx = rem / CIN_, c = rem % CIN_;
        int e = er >> 3;
        W1[idx] = f2bf(probs[e] * w_in[(er * CIN_ + c) * 3 + kx]);
    } else if (idx < 2 * M1 * K1) {
        int i2 = idx - M1 * K1;
        // W2[o][ky*64+er] = w_out[((e*256+o)*8+r)*3 + ky]
        int o = i2 / K2, rem = i2 % K2;
        if (rem < K2) {
            int ky = rem / M1, er = rem % M1;
            int e = er >> 3, r = er & 7;
            W2[i2] = f2bf(w_out[((e * COUT_ + o) * 8 + r) * 3 + ky]);
        }
    } else {
        // zero hT halo rows yp=0 and yp=65 for each b: 16*2*4096 shorts, b128
        int i3 = idx - 2 * M1 * K1;
        if (i3 < 16384) {
            int b = i3 >> 10, r = i3 & 1023;
            int yp = (r >> 9) * 65;
            int col = (r & 511) * 8;
            bf16x8 z = {};
            *(bf16x8*)(hT + ((b * 66 + yp) * 4096) + col) = z;
        }
    }
}

// -------- conv 1x3: x[16,256,64,64] f32 -> hT[16,66,64,64] bf16 (n,m) --------
// One block per (b,y). GEMM [64 x 768] * [768 x 64].
// Single-phase staging: thread loads 8c x 8n f32 block, register-transposes to
// bf16, writes 8 x ds_write_b128 into xs[ns][c] (ns = n+1 with zero halo).
__global__ __launch_bounds__(256)
void conv_in_kernel(const float* __restrict__ x,
                    const unsigned short* __restrict__ W1,
                    unsigned short* __restrict__ hT) {
    __shared__ unsigned short xs[66 * CS];
    const int bid  = blockIdx.x;
    const int b    = bid >> 6, y = bid & 63;
    const int tid  = threadIdx.x;
    const int lane = tid & 63;
    const int wave = tid >> 6;       // 4 waves; wave = m-tile
    const int g    = lane >> 4;
    const int lr   = lane & 15;

    // zero halo rows ns=0 and ns=65 (264 shorts = 33 x b64 each)
    if (tid < 66) {
        int row = (tid < 33) ? 0 : 65;
        int col = (tid - (tid < 33 ? 0 : 33)) * 8;
        bf16x4 z4 = {};
        *(bf16x4*)&xs[row * CS + col] = z4;
        *(bf16x4*)&xs[row * CS + col + 4] = z4;
    }

    // staging: thread (cb = tid&31, nb = tid>>5) covers c=cb*8..+7, n=nb*8..+7
    const int cb = tid & 31;
    const int n0 = (tid >> 5) << 3;
    const float* xp = x + (((b * CIN_ + cb * 8) * 64 + y) * 64 + n0);
    f32x4v va[8], vb[8];
    #pragma unroll
    for (int i = 0; i < 8; ++i) {
        va[i] = *(const f32x4v*)(xp + i * 4096);
        vb[i] = *(const f32x4v*)(xp + i * 4096 + 4);
    }
    #pragma unroll
    for (int j = 0; j < 4; ++j) {
        bf16x8 r0, r1;
        #pragma unroll
        for (int i = 0; i < 8; ++i) { r0[i] = (__bf16)va[i][j]; r1[i] = (__bf16)vb[i][j]; }
        *(bf16x8*)&xs[(n0 + j + 1) * CS + cb * 8] = r0;
        *(bf16x8*)&xs[(n0 + j + 5) * CS + cb * 8] = r1;
    }
    __syncthreads();

    f32x4 acc[4];
    #pragma unroll
    for (int i = 0; i < 4; ++i) acc[i] = (f32x4){0.f, 0.f, 0.f, 0.f};

    const unsigned short* w1p = W1 + (wave * 16 + lr) * K1 + g * 8;
    #pragma unroll
    for (int cc = 0; cc < 8; ++cc) {
        #pragma unroll
        for (int kx = 0; kx < 3; ++kx) {
            bf16x8 af = *(const bf16x8*)(w1p + kx * CIN_ + cc * 32);
            #pragma unroll
            for (int nt = 0; nt < 4; ++nt) {
                bf16x8 bf = *(const bf16x8*)&xs[(nt * 16 + lr + kx) * CS + cc * 32 + g * 8];
                acc[nt] = __builtin_amdgcn_mfma_f32_16x16x32_bf16(af, bf, acc[nt], 0, 0, 0);
            }
        }
    }
    // C/D: col=lr (n), row=g*4+r2 (m within wave tile). Pack 4 m -> b64 store.
    unsigned short* hp = hT + ((b * 66 + y + 1) * 64) * 64;
    #pragma unroll
    for (int nt = 0; nt < 4; ++nt) {
        int n = nt * 16 + lr;
        bf16x4 pk;
        #pragma unroll
        for (int r2 = 0; r2 < 4; ++r2) pk[r2] = (__bf16)acc[nt][r2];
        *(bf16x4*)&hp[n * 64 + wave * 16 + g * 4] = pk;
    }
}

// -------- conv 3x1: hT[16,66,64,64] bf16 -> out[16,256,64,64] f32 ------------
// One block per (b,y). GEMM [256 x 192] * [192 x 64].
// Staging: branch-free vector copy (hT rows are already [n][m]).
__global__ __launch_bounds__(256)
void conv_out_kernel(const unsigned short* __restrict__ hT,
                     const unsigned short* __restrict__ W2,
                     float* __restrict__ out) {
    __shared__ unsigned short hs[64 * HS];
    const int bid  = blockIdx.x;
    const int b    = bid >> 6, y = bid & 63;
    const int tid  = threadIdx.x;
    const int lane = tid & 63;
    const int wave = tid >> 6;       // wave -> o-tiles [wave*4, wave*4+4)
    const int g    = lane >> 4;
    const int lr   = lane & 15;

    if (tid < 192) {   // ky = tid>>6, xr = tid&63: copy one 128B row
        int ky = tid >> 6, xr = tid & 63;
        const unsigned short* src = hT + (((b * 66) + y + ky) * 64 + xr) * 64;
        unsigned short* dst = &hs[xr * HS + ky * 64];
        #pragma unroll
        for (int j = 0; j < 8; ++j)
            *(bf16x8*)&dst[j * 8] = *(const bf16x8*)&src[j * 8];
    }
    __syncthreads();

    f32x4 acc[4][4];
    #pragma unroll
    for (int ot = 0; ot < 4; ++ot)
        #pragma unroll
        for (int nt = 0; nt < 4; ++nt) acc[ot][nt] = (f32x4){0.f, 0.f, 0.f, 0.f};

    #pragma unroll
    for (int kc = 0; kc < 6; ++kc) {
        bf16x8 bfrag[4];
        #pragma unroll
        for (int nt = 0; nt < 4; ++nt)
            bfrag[nt] = *(const bf16x8*)&hs[(nt * 16 + lr) * HS + kc * 32 + g * 8];
        #pragma unroll
        for (int ot = 0; ot < 4; ++ot) {
            bf16x8 af = *(const bf16x8*)(W2 + ((wave * 4 + ot) * 16 + lr) * K2 +
                                         kc * 32 + g * 8);
            #pragma unroll
            for (int nt = 0; nt < 4; ++nt)
                acc[ot][nt] = __builtin_amdgcn_mfma_f32_16x16x32_bf16(af, bfrag[nt],
                                                                      acc[ot][nt], 0, 0, 0);
        }
    }

    #pragma unroll
    for (int ot = 0; ot < 4; ++ot) {
        #pragma unroll
        for (int r2 = 0; r2 < 4; ++r2) {
            int o = (wave * 4 + ot) * 16 + g * 4 + r2;
            float* orow = out + ((b * COUT_ + o) * 64 + y) * 64;
            #pragma unroll
            for (int nt = 0; nt < 4; ++nt)
                orow[nt * 16 + lr] = acc[ot][nt][r2];
        }
    }
}

extern "C" void kernel_launch(void* const* d_in, const int* in_sizes, int n_in,
                              void* d_out, int out_size, void* d_ws, size_t ws_size,
                              hipStream_t stream) {
    const float* x     = (const float*)d_in[0];   // [16,256,64,64]
    const float* probs = (const float*)d_in[1];   // [8]
    const float* w_in  = (const float*)d_in[2];   // [8,8,256,1,3]
    const float* w_out = (const float*)d_in[3];   // [8,256,8,3,1]
    float* out = (float*)d_out;                   // [16,256,64,64] f32

    unsigned short* W1 = (unsigned short*)d_ws;          // 64*768 bf16
    unsigned short* W2 = W1 + M1 * K1;                   // 256*192 bf16
    unsigned short* hT = W2 + COUT_ * K2;                // 16*66*64*64 bf16 (8.65MB)

    // grid covers: W1 (49152) + W2 (49152) + hT halo zero (16384 b128 chunks)
    prep_weights<<<(2 * M1 * K1 + 16384 + 255) / 256, 256, 0, stream>>>(
        probs, w_in, w_out, W1, W2, hT);
    conv_in_kernel<<<16 * 64, 256, 0, stream>>>(x, W1, hT);
    conv_out_kernel<<<16 * 64, 256, 0, stream>>>(hT, W2, out);
}

// Round 3
// 56.664 us; speedup vs baseline: 1.0206x; 1.0206x over previous
//
#include <hip/hip_runtime.h>
#include <hip/hip_bf16.h>

// LoRA conv experts, algebraically collapsed:
//   out = sum_e p_e * Conv3x1(w_out_e) ( Conv1x3(w_in_e) (x) )
// Folded into ONE rank-64 separable pair (exact, convs are linear):
//   W1[(e,r)][kx*256+c] = p_e * w_in[e,r,c,0,kx]    (64 x 768)
//   W2[o][ky*64+(e,r)]  = w_out[e,o,r,ky,0]         (256 x 192)
//   hT = conv1x3(x, W1) stored TRANSPOSED+PADDED hT[b][y+1][n][m].
// R3: coalesced global transactions (wave reads full 256B rows of x; conv_out
// staging 8 lanes/row), XOR-swizzled LDS transpose writes.

typedef __bf16 bf16x8 __attribute__((ext_vector_type(8)));
typedef __bf16 bf16x4 __attribute__((ext_vector_type(4)));
typedef float  f32x4  __attribute__((ext_vector_type(4)));

#define CIN_  256
#define COUT_ 256
#define M1    64      // E*R
#define K1    768     // 3*CIN
#define K2    192     // 3*M1
#define CS    264     // xs row stride (shorts)
#define HS    200     // hs row stride (shorts)

static __device__ __forceinline__ unsigned short f2bf(float f) {
    union { float f; unsigned u; } v; v.f = f;
    unsigned r = v.u + 0x7FFFu + ((v.u >> 16) & 1u);
    return (unsigned short)(r >> 16);
}

// ------------- prep: fold probs, reorder, cast; zero hT halo rows ------------
__global__ void prep_weights(const float* __restrict__ probs,
                             const float* __restrict__ w_in,
                             const float* __restrict__ w_out,
                             unsigned short* __restrict__ W1,
                             unsigned short* __restrict__ W2,
                             unsigned short* __restrict__ hT) {
    int idx = blockIdx.x * blockDim.x + threadIdx.x;
    if (idx < M1 * K1) {
        int er = idx / K1, rem = idx % K1;
        int kx = rem / CIN_, c = rem % CIN_;
        int e = er >> 3;
        W1[idx] = f2bf(probs[e] * w_in[(er * CIN_ + c) * 3 + kx]);
    } else if (idx < 2 * M1 * K1) {
        int i2 = idx - M1 * K1;
        int o = i2 / K2, rem = i2 % K2;
        int ky = rem / M1, er = rem % M1;
        int e = er >> 3, r = er & 7;
        W2[i2] = f2bf(w_out[((e * COUT_ + o) * 8 + r) * 3 + ky]);
    } else {
        int i3 = idx - 2 * M1 * K1;
        if (i3 < 16384) {   // zero hT halo rows yp=0,65 per b (b128 chunks)
            int b = i3 >> 10, r = i3 & 1023;
            int yp = (r >> 9) * 65;
            int col = (r & 511) * 8;
            bf16x8 z = {};
            *(bf16x8*)(hT + ((b * 66 + yp) * 4096) + col) = z;
        }
    }
}

// -------- conv 1x3: x[16,256,64,64] f32 -> hT[16,66,64,64] bf16 (n,m) --------
// One block per (b,y). GEMM [64 x 768] * [768 x 64].
// Coalesced staging: wave-load = 4 full 256B c-rows; transpose via scalar b16
// LDS writes with XOR swizzle  c ^= ((n>>2)&7)<<3  (readers apply same XOR).
__global__ __launch_bounds__(256, 4)
void conv_in_kernel(const float* __restrict__ x,
                    const unsigned short* __restrict__ W1,
                    unsigned short* __restrict__ hT) {
    __shared__ unsigned short xs[66 * CS];
    const int bid  = blockIdx.x;
    const int b    = bid >> 6, y = bid & 63;
    const int tid  = threadIdx.x;
    const int lane = tid & 63;
    const int wave = tid >> 6;       // 4 waves; wave = m-tile
    const int g    = lane >> 4;
    const int lr   = lane & 15;

    // zero halo rows ns=0 and ns=65 (swizzle is a permutation within the row,
    // so whole-row zeroing is swizzle-safe)
    if (tid < 66) {
        int row = (tid < 33) ? 0 : 65;
        int col = (tid - (tid < 33 ? 0 : 33)) * 8;
        bf16x4 z4 = {};
        *(bf16x4*)&xs[row * CS + col] = z4;
        *(bf16x4*)&xs[row * CS + col + 4] = z4;
    }

    // staging: thread t -> c-row = it*16 + (t>>4), n-quad = (t&15)*4
    const int crow = tid >> 4;
    const int n4   = (tid & 15) << 2;
    const int swzt = (tid & 7) << 3;          // ((n4>>2)&7)<<3
    const float* xbase = x + ((b * CIN_ + crow) * 64 + y) * 64 + n4;
    unsigned short* wr = &xs[(n4 + 1) * CS];

    #pragma unroll
    for (int r = 0; r < 4; ++r) {
        float4 ld[4];
        #pragma unroll
        for (int q = 0; q < 4; ++q)
            ld[q] = *(const float4*)(xbase + (r * 4 + q) * 16 * 4096);
        #pragma unroll
        for (int q = 0; q < 4; ++q) {
            int cx = ((r * 4 + q) * 16 + crow) ^ swzt;
            wr[0 * CS + cx] = f2bf(ld[q].x);
            wr[1 * CS + cx] = f2bf(ld[q].y);
            wr[2 * CS + cx] = f2bf(ld[q].z);
            wr[3 * CS + cx] = f2bf(ld[q].w);
        }
    }
    __syncthreads();

    f32x4 acc[4];
    #pragma unroll
    for (int i = 0; i < 4; ++i) acc[i] = (f32x4){0.f, 0.f, 0.f, 0.f};

    const unsigned short* w1p = W1 + (wave * 16 + lr) * K1 + g * 8;
    #pragma unroll
    for (int kx = 0; kx < 3; ++kx) {
        bf16x8 af[8];
        #pragma unroll
        for (int cc = 0; cc < 8; ++cc)
            af[cc] = *(const bf16x8*)(w1p + kx * CIN_ + cc * 32);
        int ns0 = lr + kx;
        int sz0 = (((ns0 - 1) >> 2) & 7) << 3;
        int ns1 = ns0 + 16, sz1 = (((ns1 - 1) >> 2) & 7) << 3;
        int ns2 = ns0 + 32, sz2 = (((ns2 - 1) >> 2) & 7) << 3;
        int ns3 = ns0 + 48, sz3 = (((ns3 - 1) >> 2) & 7) << 3;
        const unsigned short* r0 = &xs[ns0 * CS];
        const unsigned short* r1 = &xs[ns1 * CS];
        const unsigned short* r2p = &xs[ns2 * CS];
        const unsigned short* r3 = &xs[ns3 * CS];
        #pragma unroll
        for (int cc = 0; cc < 8; ++cc) {
            int co = cc * 32 + g * 8;
            acc[0] = __builtin_amdgcn_mfma_f32_16x16x32_bf16(
                af[cc], *(const bf16x8*)&r0[co ^ sz0], acc[0], 0, 0, 0);
            acc[1] = __builtin_amdgcn_mfma_f32_16x16x32_bf16(
                af[cc], *(const bf16x8*)&r1[co ^ sz1], acc[1], 0, 0, 0);
            acc[2] = __builtin_amdgcn_mfma_f32_16x16x32_bf16(
                af[cc], *(const bf16x8*)&r2p[co ^ sz2], acc[2], 0, 0, 0);
            acc[3] = __builtin_amdgcn_mfma_f32_16x16x32_bf16(
                af[cc], *(const bf16x8*)&r3[co ^ sz3], acc[3], 0, 0, 0);
        }
    }
    // C/D: col=lr (n), row=g*4+r2 (m). Pack 4 m -> b64 store.
    unsigned short* hp = hT + ((b * 66 + y + 1) * 64) * 64;
    #pragma unroll
    for (int nt = 0; nt < 4; ++nt) {
        int n = nt * 16 + lr;
        bf16x4 pk;
        #pragma unroll
        for (int r2 = 0; r2 < 4; ++r2) pk[r2] = (__bf16)acc[nt][r2];
        *(bf16x4*)&hp[n * 64 + wave * 16 + g * 4] = pk;
    }
}

// -------- conv 3x1: hT[16,66,64,64] bf16 -> out[16,256,64,64] f32 ------------
// One block per (b,y). GEMM [256 x 192] * [192 x 64].
// Staging: 8 consecutive lanes cover one 128B hT row (coalesced).
__global__ __launch_bounds__(256, 4)
void conv_out_kernel(const unsigned short* __restrict__ hT,
                     const unsigned short* __restrict__ W2,
                     float* __restrict__ out) {
    __shared__ unsigned short hs[64 * HS];
    const int bid  = blockIdx.x;
    const int b    = bid >> 6, y = bid & 63;
    const int tid  = threadIdx.x;
    const int lane = tid & 63;
    const int wave = tid >> 6;       // wave -> o-tiles [wave*4, wave*4+4)
    const int g    = lane >> 4;
    const int lr   = lane & 15;

    // staging: 192 rows x 128B; thread t iter v: row = v*32+(t>>3), off=(t&7)*16B
    const int rrow = tid >> 3;
    const int u8   = (tid & 7) * 8;
    #pragma unroll
    for (int v = 0; v < 6; ++v) {
        int R  = v * 32 + rrow;          // 0..191
        int ky = R >> 6, xr = R & 63;
        const unsigned short* src = hT + (((b * 66) + y + ky) * 64 + xr) * 64 + u8;
        *(bf16x8*)&hs[xr * HS + ky * 64 + u8] = *(const bf16x8*)src;
    }
    __syncthreads();

    f32x4 acc[4][4];
    #pragma unroll
    for (int ot = 0; ot < 4; ++ot)
        #pragma unroll
        for (int nt = 0; nt < 4; ++nt) acc[ot][nt] = (f32x4){0.f, 0.f, 0.f, 0.f};

    #pragma unroll
    for (int kc = 0; kc < 6; ++kc) {
        bf16x8 bfrag[4];
        #pragma unroll
        for (int nt = 0; nt < 4; ++nt)
            bfrag[nt] = *(const bf16x8*)&hs[(nt * 16 + lr) * HS + kc * 32 + g * 8];
        #pragma unroll
        for (int ot = 0; ot < 4; ++ot) {
            bf16x8 af = *(const bf16x8*)(W2 + ((wave * 4 + ot) * 16 + lr) * K2 +
                                         kc * 32 + g * 8);
            #pragma unroll
            for (int nt = 0; nt < 4; ++nt)
                acc[ot][nt] = __builtin_amdgcn_mfma_f32_16x16x32_bf16(af, bfrag[nt],
                                                                      acc[ot][nt], 0, 0, 0);
        }
    }

    #pragma unroll
    for (int ot = 0; ot < 4; ++ot) {
        #pragma unroll
        for (int r2 = 0; r2 < 4; ++r2) {
            int o = (wave * 4 + ot) * 16 + g * 4 + r2;
            float* orow = out + ((b * COUT_ + o) * 64 + y) * 64;
            #pragma unroll
            for (int nt = 0; nt < 4; ++nt)
                orow[nt * 16 + lr] = acc[ot][nt][r2];
        }
    }
}

extern "C" void kernel_launch(void* const* d_in, const int* in_sizes, int n_in,
                              void* d_out, int out_size, void* d_ws, size_t ws_size,
                              hipStream_t stream) {
    const float* x     = (const float*)d_in[0];   // [16,256,64,64]
    const float* probs = (const float*)d_in[1];   // [8]
    const float* w_in  = (const float*)d_in[2];   // [8,8,256,1,3]
    const float* w_out = (const float*)d_in[3];   // [8,256,8,3,1]
    float* out = (float*)d_out;                   // [16,256,64,64] f32

    unsigned short* W1 = (unsigned short*)d_ws;          // 64*768 bf16
    unsigned short* W2 = W1 + M1 * K1;                   // 256*192 bf16
    unsigned short* hT = W2 + COUT_ * K2;                // 16*66*64*64 bf16 (8.65MB)

    prep_weights<<<(2 * M1 * K1 + 16384 + 255) / 256, 256, 0, stream>>>(
        probs, w_in, w_out, W1, W2, hT);
    conv_in_kernel<<<16 * 64, 256, 0, stream>>>(x, W1, hT);
    conv_out_kernel<<<16 * 64, 256, 0, stream>>>(hT, W2, out);
}

// Round 4
// 49.246 us; speedup vs baseline: 1.1744x; 1.1506x over previous
//
#include <hip/hip_runtime.h>
#include <hip/hip_bf16.h>

// LoRA conv experts, algebraically collapsed into ONE rank-64 separable pair:
//   W1[(e,r)][kx*256+c] = p_e * w_in[e,r,c,0,kx]    (64 x 768)
//   W2[o][ky*64+(e,r)]  = w_out[e,o,r,ky,0]         (256 x 192)
// R4: FUSED kernel. Block = (b, y-stripe of 2). Computes 4 halo h-rows
// (y0-1..y0+2) into LDS, then the 2 output rows. Eliminates hT round-trip
// and 2 kernel boundaries. h rows out of [0,64) are exact zeros (zero x).

typedef __bf16 bf16x8 __attribute__((ext_vector_type(8)));
typedef __bf16 bf16x4 __attribute__((ext_vector_type(4)));
typedef float  f32x4  __attribute__((ext_vector_type(4)));

#define CIN_  256
#define COUT_ 256
#define M1    64
#define K1    768
#define K2    192
#define CS    264     // xs row stride (shorts)
#define HS2   264     // hs row stride (shorts), cols 0..255 = yy*64+m

static __device__ __forceinline__ unsigned short f2bf(float f) {
    union { float f; unsigned u; } v; v.f = f;
    unsigned r = v.u + 0x7FFFu + ((v.u >> 16) & 1u);
    return (unsigned short)(r >> 16);
}

// ------------- prep: fold probs, reorder, cast to bf16 (W1, W2) -------------
__global__ void prep_weights(const float* __restrict__ probs,
                             const float* __restrict__ w_in,
                             const float* __restrict__ w_out,
                             unsigned short* __restrict__ W1,
                             unsigned short* __restrict__ W2) {
    int idx = blockIdx.x * blockDim.x + threadIdx.x;
    if (idx < M1 * K1) {
        int er = idx / K1, rem = idx % K1;
        int kx = rem / CIN_, c = rem % CIN_;
        int e = er >> 3;
        W1[idx] = f2bf(probs[e] * w_in[(er * CIN_ + c) * 3 + kx]);
    } else {
        int i2 = idx - M1 * K1;   // grid sized exactly: i2 < COUT_*K2
        int o = i2 / K2, rem = i2 % K2;
        int ky = rem / M1, er = rem % M1;
        int e = er >> 3, r = er & 7;
        W2[i2] = f2bf(w_out[((e * COUT_ + o) * 8 + r) * 3 + ky]);
    }
}

// ----------------------------- fused conv kernel -----------------------------
// grid = 16 b * 32 stripes = 512 blocks, 256 threads (4 waves), 67KB LDS.
__global__ __launch_bounds__(256, 2)
void fused_kernel(const float* __restrict__ x,
                  const unsigned short* __restrict__ W1,
                  const unsigned short* __restrict__ W2,
                  float* __restrict__ out) {
    __shared__ unsigned short xs[66 * CS];   // x row tile, transposed [ns][c]
    __shared__ unsigned short hs[64 * HS2];  // h tile [n][yy*64+m], XOR-swizzled
    const int bid  = blockIdx.x;
    const int b    = bid >> 5;
    const int y0   = (bid & 31) << 1;
    const int tid  = threadIdx.x;
    const int lane = tid & 63;
    const int wave = tid >> 6;       // wave = m-tile for h-phase
    const int g    = lane >> 4;
    const int lr   = lane & 15;

    // hoist W1 fragments for this wave's m-row (24 frags = 96 VGPR)
    bf16x8 w1f[3][8];
    {
        const unsigned short* w1p = W1 + (wave * 16 + lr) * K1 + g * 8;
        #pragma unroll
        for (int kx = 0; kx < 3; ++kx)
            #pragma unroll
            for (int cc = 0; cc < 8; ++cc)
                w1f[kx][cc] = *(const bf16x8*)(w1p + kx * CIN_ + cc * 32);
    }

    // zero xs halo rows ns=0 (n=-1) and ns=65 (n=64), once
    if (tid < 66) {
        int row = (tid < 33) ? 0 : 65;
        int col = (tid - (tid < 33 ? 0 : 33)) * 8;
        bf16x4 z4 = {};
        *(bf16x4*)&xs[row * CS + col] = z4;
        *(bf16x4*)&xs[row * CS + col + 4] = z4;
    }

    // staging map (R3-proven): thread t -> c-row = t>>4, n-quad = (t&15)*4
    const int crow = tid >> 4;
    const int n4   = (tid & 15) << 2;
    const int swzt = (tid & 7) << 3;          // ((n4>>2)&7)<<3

    // ---------------- h-phase: 4 rows y = y0-1 .. y0+2 ----------------
    for (int yy = 0; yy < 4; ++yy) {
        const int y = y0 - 1 + yy;
        const bool yok = ((unsigned)y < 64u);
        __syncthreads();                      // xs free (prev row's readers done)
        const float* xbase = x + ((b * CIN_ + crow) * 64 + (yok ? y : 0)) * 64 + n4;
        unsigned short* wr = &xs[(n4 + 1) * CS];
        #pragma unroll
        for (int r = 0; r < 4; ++r) {
            float4 ld[4];
            if (yok) {
                #pragma unroll
                for (int q = 0; q < 4; ++q)
                    ld[q] = *(const float4*)(xbase + (r * 4 + q) * 16 * 4096);
            } else {
                #pragma unroll
                for (int q = 0; q < 4; ++q) ld[q] = make_float4(0.f, 0.f, 0.f, 0.f);
            }
            #pragma unroll
            for (int q = 0; q < 4; ++q) {
                int cx = ((r * 4 + q) * 16 + crow) ^ swzt;
                wr[0 * CS + cx] = f2bf(ld[q].x);
                wr[1 * CS + cx] = f2bf(ld[q].y);
                wr[2 * CS + cx] = f2bf(ld[q].z);
                wr[3 * CS + cx] = f2bf(ld[q].w);
            }
        }
        __syncthreads();                      // xs ready

        f32x4 acc[4];
        #pragma unroll
        for (int i = 0; i < 4; ++i) acc[i] = (f32x4){0.f, 0.f, 0.f, 0.f};
        #pragma unroll
        for (int kx = 0; kx < 3; ++kx) {
            int ns0 = lr + kx;
            int sz0 = (((ns0 - 1) >> 2) & 7) << 3;
            int ns1 = ns0 + 16, sz1 = (((ns1 - 1) >> 2) & 7) << 3;
            int ns2 = ns0 + 32, sz2 = (((ns2 - 1) >> 2) & 7) << 3;
            int ns3 = ns0 + 48, sz3 = (((ns3 - 1) >> 2) & 7) << 3;
            const unsigned short* r0  = &xs[ns0 * CS];
            const unsigned short* r1  = &xs[ns1 * CS];
            const unsigned short* r2p = &xs[ns2 * CS];
            const unsigned short* r3  = &xs[ns3 * CS];
            #pragma unroll
            for (int cc = 0; cc < 8; ++cc) {
                int co = cc * 32 + g * 8;
                acc[0] = __builtin_amdgcn_mfma_f32_16x16x32_bf16(
                    w1f[kx][cc], *(const bf16x8*)&r0[co ^ sz0], acc[0], 0, 0, 0);
                acc[1] = __builtin_amdgcn_mfma_f32_16x16x32_bf16(
                    w1f[kx][cc], *(const bf16x8*)&r1[co ^ sz1], acc[1], 0, 0, 0);
                acc[2] = __builtin_amdgcn_mfma_f32_16x16x32_bf16(
                    w1f[kx][cc], *(const bf16x8*)&r2p[co ^ sz2], acc[2], 0, 0, 0);
                acc[3] = __builtin_amdgcn_mfma_f32_16x16x32_bf16(
                    w1f[kx][cc], *(const bf16x8*)&r3[co ^ sz3], acc[3], 0, 0, 0);
            }
        }
        // D: col=lr (n), row=g*4+r2 (m). Write h row into hs (swizzled cols).
        #pragma unroll
        for (int nt = 0; nt < 4; ++nt) {
            int n = nt * 16 + lr;
            bf16x4 pk;
            #pragma unroll
            for (int r2 = 0; r2 < 4; ++r2) pk[r2] = (__bf16)acc[nt][r2];
            int col = (yy * 64 + wave * 16 + g * 4) ^ ((n & 7) << 3);
            *(bf16x4*)&hs[n * HS2 + col] = pk;
        }
    }
    __syncthreads();                          // hs complete

    // ---------------- conv_out phase: 2 output rows ----------------
    bf16x8 w2f[4][6];                         // 24 frags = 96 VGPR (W1 regs dead)
    #pragma unroll
    for (int ot = 0; ot < 4; ++ot)
        #pragma unroll
        for (int kc = 0; kc < 6; ++kc)
            w2f[ot][kc] = *(const bf16x8*)(W2 + ((wave * 4 + ot) * 16 + lr) * K2 +
                                           kc * 32 + g * 8);

    #pragma unroll
    for (int ry = 0; ry < 2; ++ry) {
        f32x4 acc2[4][4];
        #pragma unroll
        for (int ot = 0; ot < 4; ++ot)
            #pragma unroll
            for (int nt = 0; nt < 4; ++nt) acc2[ot][nt] = (f32x4){0.f, 0.f, 0.f, 0.f};

        #pragma unroll
        for (int kc = 0; kc < 6; ++kc) {
            bf16x8 bfrag[4];
            #pragma unroll
            for (int nt = 0; nt < 4; ++nt) {
                int n = nt * 16 + lr;
                int col = (ry * 64 + kc * 32 + g * 8) ^ ((n & 7) << 3);
                bfrag[nt] = *(const bf16x8*)&hs[n * HS2 + col];
            }
            #pragma unroll
            for (int ot = 0; ot < 4; ++ot)
                #pragma unroll
                for (int nt = 0; nt < 4; ++nt)
                    acc2[ot][nt] = __builtin_amdgcn_mfma_f32_16x16x32_bf16(
                        w2f[ot][kc], bfrag[nt], acc2[ot][nt], 0, 0, 0);
        }

        const int yo = y0 + ry;
        #pragma unroll
        for (int ot = 0; ot < 4; ++ot) {
            #pragma unroll
            for (int r2 = 0; r2 < 4; ++r2) {
                int o = (wave * 4 + ot) * 16 + g * 4 + r2;
                float* orow = out + ((b * COUT_ + o) * 64 + yo) * 64;
                #pragma unroll
                for (int nt = 0; nt < 4; ++nt)
                    orow[nt * 16 + lr] = acc2[ot][nt][r2];
            }
        }
    }
}

extern "C" void kernel_launch(void* const* d_in, const int* in_sizes, int n_in,
                              void* d_out, int out_size, void* d_ws, size_t ws_size,
                              hipStream_t stream) {
    const float* x     = (const float*)d_in[0];   // [16,256,64,64]
    const float* probs = (const float*)d_in[1];   // [8]
    const float* w_in  = (const float*)d_in[2];   // [8,8,256,1,3]
    const float* w_out = (const float*)d_in[3];   // [8,256,8,3,1]
    float* out = (float*)d_out;                   // [16,256,64,64] f32

    unsigned short* W1 = (unsigned short*)d_ws;   // 64*768 bf16
    unsigned short* W2 = W1 + M1 * K1;            // 256*192 bf16

    // 2*M1*K1 = 98304 = 384*256 exactly (M1*K1 == COUT_*K2)
    prep_weights<<<384, 256, 0, stream>>>(probs, w_in, w_out, W1, W2);
    fused_kernel<<<16 * 32, 256, 0, stream>>>(x, W1, W2, out);
}